// Round 1
// baseline (361.002 us; speedup 1.0000x reference)
//
#include <hip/hip_runtime.h>
#include <hip/hip_bf16.h>

// Problem dims (fixed by setup_inputs):
//   B=4, S=2048, H=1024, NH=16, D=64, M = B*S = 8192
#define S_LEN   2048
#define NHEADS  16
#define HDIM    64
#define HID     1024
#define BATCH   4
#define M_ROWS  (BATCH * S_LEN)   // 8192

typedef __attribute__((ext_vector_type(8))) short short8;
typedef __attribute__((ext_vector_type(4))) float floatx4;

__device__ __forceinline__ unsigned short f2bf_rne(float x) {
  union { float f; unsigned u; } v; v.f = x;
  unsigned r = v.u + 0x7fffu + ((v.u >> 16) & 1u);
  return (unsigned short)(r >> 16);
}

// ---------------- fp32 -> bf16 cast (vectorized x4) ----------------
__global__ __launch_bounds__(256) void cast_f32_bf16(const float* __restrict__ in,
                                                     unsigned short* __restrict__ out,
                                                     int n4) {
  int idx = blockIdx.x * 256 + threadIdx.x;
  if (idx >= n4) return;
  float4 v = ((const float4*)in)[idx];
  ushort4 o;
  o.x = f2bf_rne(v.x);
  o.y = f2bf_rne(v.y);
  o.z = f2bf_rne(v.z);
  o.w = f2bf_rne(v.w);
  ((ushort4*)out)[idx] = o;
}

// ---------------- QKV projection GEMM ----------------
// C[m,n] = sum_k A[m,k] * W[n,k] + bias[n]    (A: M x K bf16, W: N x K bf16)
// Block tile 64x64, BK=32, 256 threads = 4 waves in 2x2, each wave 32x32
// (2x2 MFMA 16x16x32 tiles). Output fp32. grid.z selects {Wq,Wk,Wv}.
__global__ __launch_bounds__(256) void qkv_gemm(
    const unsigned short* __restrict__ A,
    const unsigned short* __restrict__ W0, const unsigned short* __restrict__ W1,
    const unsigned short* __restrict__ W2,
    const float* __restrict__ b0, const float* __restrict__ b1,
    const float* __restrict__ b2,
    float* __restrict__ O0, float* __restrict__ O1, float* __restrict__ O2) {
  const int K = HID;
  const int N = HID;
  const int z = blockIdx.z;
  const unsigned short* __restrict__ W = (z == 0) ? W0 : (z == 1) ? W1 : W2;
  const float* __restrict__ bias = (z == 0) ? b0 : (z == 1) ? b1 : b2;
  float* __restrict__ O = (z == 0) ? O0 : (z == 1) ? O1 : O2;

  // +8 pad on the 32-wide row breaks the power-of-2 bank stride
  __shared__ unsigned short As[64][40];
  __shared__ unsigned short Bs[64][40];

  const int tid = threadIdx.x;
  const int m0 = blockIdx.x * 64;
  const int n0 = blockIdx.y * 64;

  // staging: each thread loads one 16B chunk (8 bf16) of A and of W per stage
  const int sr = tid >> 2;          // 0..63
  const int sc = (tid & 3) << 3;    // 0,8,16,24

  const int wave = tid >> 6;        // 0..3
  const int lane = tid & 63;
  const int wm = (wave & 1) << 5;   // 0 or 32
  const int wn = (wave >> 1) << 5;  // 0 or 32
  const int lrow = lane & 15;
  const int qd = lane >> 4;         // quad 0..3

  floatx4 acc[2][2] = {};

  const size_t a_base = (size_t)(m0 + sr) * K + sc;
  const size_t w_base = (size_t)(n0 + sr) * K + sc;

  for (int k0 = 0; k0 < K; k0 += 32) {
    *(uint4*)(&As[sr][sc]) = *(const uint4*)(&A[a_base + k0]);
    *(uint4*)(&Bs[sr][sc]) = *(const uint4*)(&W[w_base + k0]);
    __syncthreads();

    short8 a0  = *(const short8*)(&As[wm + lrow][qd << 3]);
    short8 a1  = *(const short8*)(&As[wm + 16 + lrow][qd << 3]);
    short8 bv0 = *(const short8*)(&Bs[wn + lrow][qd << 3]);
    short8 bv1 = *(const short8*)(&Bs[wn + 16 + lrow][qd << 3]);

    acc[0][0] = __builtin_amdgcn_mfma_f32_16x16x32_bf16(a0, bv0, acc[0][0], 0, 0, 0);
    acc[0][1] = __builtin_amdgcn_mfma_f32_16x16x32_bf16(a0, bv1, acc[0][1], 0, 0, 0);
    acc[1][0] = __builtin_amdgcn_mfma_f32_16x16x32_bf16(a1, bv0, acc[1][0], 0, 0, 0);
    acc[1][1] = __builtin_amdgcn_mfma_f32_16x16x32_bf16(a1, bv1, acc[1][1], 0, 0, 0);
    __syncthreads();
  }

  // epilogue: C/D layout col = lane&15, row = quad*4 + r
  #pragma unroll
  for (int im = 0; im < 2; ++im) {
    #pragma unroll
    for (int in = 0; in < 2; ++in) {
      const int col = n0 + wn + in * 16 + lrow;
      const float bb = bias[col];
      #pragma unroll
      for (int r = 0; r < 4; ++r) {
        const int row = m0 + wm + im * 16 + (qd << 2) + r;
        O[(size_t)row * N + col] = acc[im][in][r] + bb;
      }
    }
  }
}

// ---------------- log-sparse attention ----------------
// One wave per (b, h, i); lane = head dim. Keys: j = i, i-1, i-2, i-4, ...
// Q,K,V layout: [b, s, h, d] fp32 (the GEMM output layout, n = h*64+d).
__global__ __launch_bounds__(256) void logsparse_attn(
    const float* __restrict__ Q, const float* __restrict__ K,
    const float* __restrict__ V, const float* __restrict__ mask,
    float* __restrict__ out) {
  const int wid  = (blockIdx.x * 256 + threadIdx.x) >> 6;  // global wave id
  const int lane = threadIdx.x & 63;

  const int i = wid & (S_LEN - 1);
  const int h = (wid >> 11) & (NHEADS - 1);
  const int b = wid >> 15;

  const size_t base = (size_t)b * S_LEN * HID + h * HDIM + lane;

  const float q = Q[base + (size_t)i * HID];

  int js[12];
  js[0] = i;
  int nj = 1;
  for (int dlt = 1; dlt <= i; dlt <<= 1) js[nj++] = i - dlt;
  #pragma unroll
  for (int t = 1; t < 12; ++t) {
    if (t >= nj) js[t] = i;  // harmless pad
  }

  float s[12];
  #pragma unroll
  for (int t = 0; t < 12; ++t) {
    const int j = js[t];
    float p = q * K[base + (size_t)j * HID];
    #pragma unroll
    for (int off = 32; off; off >>= 1) p += __shfl_xor(p, off, 64);
    s[t] = (t < nj) ? (p * 0.125f + mask[b * S_LEN + j]) : -1e30f;
  }

  float mx = s[0];
  #pragma unroll
  for (int t = 1; t < 12; ++t) mx = fmaxf(mx, s[t]);
  float l = 0.f;
  #pragma unroll
  for (int t = 0; t < 12; ++t) { s[t] = __expf(s[t] - mx); l += s[t]; }
  const float inv = 1.f / l;

  float o = 0.f;
  #pragma unroll
  for (int t = 0; t < 12; ++t) {
    o += s[t] * V[base + (size_t)js[t] * HID];
  }
  out[base + (size_t)i * HID] = o * inv;
}

// ---------------- launch ----------------
extern "C" void kernel_launch(void* const* d_in, const int* in_sizes, int n_in,
                              void* d_out, int out_size, void* d_ws, size_t ws_size,
                              hipStream_t stream) {
  const float* hs   = (const float*)d_in[0];
  const float* mask = (const float*)d_in[1];
  const float* Wq   = (const float*)d_in[2];
  const float* bq   = (const float*)d_in[3];
  const float* Wk   = (const float*)d_in[4];
  const float* bk   = (const float*)d_in[5];
  const float* Wv   = (const float*)d_in[6];
  const float* bv   = (const float*)d_in[7];
  float* out = (float*)d_out;

  // workspace layout
  unsigned short* hsb = (unsigned short*)d_ws;                  // M*H bf16
  unsigned short* wqb = hsb + (size_t)M_ROWS * HID;             // H*H bf16
  unsigned short* wkb = wqb + (size_t)HID * HID;
  unsigned short* wvb = wkb + (size_t)HID * HID;
  float* Qf = (float*)(wvb + (size_t)HID * HID);                // M*H fp32
  float* Kf = Qf + (size_t)M_ROWS * HID;
  float* Vf = Kf + (size_t)M_ROWS * HID;

  // casts
  {
    int n4 = (M_ROWS * HID) / 4;
    cast_f32_bf16<<<n4 / 256, 256, 0, stream>>>(hs, hsb, n4);
    int w4 = (HID * HID) / 4;
    cast_f32_bf16<<<w4 / 256, 256, 0, stream>>>(Wq, wqb, w4);
    cast_f32_bf16<<<w4 / 256, 256, 0, stream>>>(Wk, wkb, w4);
    cast_f32_bf16<<<w4 / 256, 256, 0, stream>>>(Wv, wvb, w4);
  }

  // QKV projections
  {
    dim3 grid(M_ROWS / 64, HID / 64, 3);
    qkv_gemm<<<grid, 256, 0, stream>>>(hsb, wqb, wkb, wvb, bq, bk, bv, Qf, Kf, Vf);
  }

  // sparse attention
  {
    int waves = BATCH * NHEADS * S_LEN;          // 131072
    int blocks = waves * 64 / 256;               // 32768
    logsparse_attn<<<blocks, 256, 0, stream>>>(Qf, Kf, Vf, mask, out);
  }
}

// Round 2
// 232.910 us; speedup vs baseline: 1.5500x; 1.5500x over previous
//
#include <hip/hip_runtime.h>
#include <hip/hip_bf16.h>

// Problem dims (fixed by setup_inputs):
//   B=4, S=2048, H=1024, NH=16, D=64, M = B*S = 8192
#define S_LEN   2048
#define NHEADS  16
#define HDIM    64
#define HID     1024
#define BATCH   4
#define M_ROWS  (BATCH * S_LEN)   // 8192

#define BM 128
#define BN 128
#define BK 32

typedef __attribute__((ext_vector_type(8))) short short8;
typedef __attribute__((ext_vector_type(4))) float floatx4;

__device__ __forceinline__ unsigned short f2bf_rne(float x) {
  union { float f; unsigned u; } v; v.f = x;
  unsigned r = v.u + 0x7fffu + ((v.u >> 16) & 1u);
  return (unsigned short)(r >> 16);
}

__device__ __forceinline__ void glds16(const unsigned short* g, unsigned short* l) {
  __builtin_amdgcn_global_load_lds(
      (const __attribute__((address_space(1))) unsigned int*)g,
      (__attribute__((address_space(3))) unsigned int*)l, 16, 0, 0);
}

// ---------------- fp32 -> bf16 cast (vectorized x4) ----------------
__global__ __launch_bounds__(256) void cast_f32_bf16(const float* __restrict__ in,
                                                     unsigned short* __restrict__ out,
                                                     int n4) {
  int idx = blockIdx.x * 256 + threadIdx.x;
  if (idx >= n4) return;
  float4 v = ((const float4*)in)[idx];
  ushort4 o;
  o.x = f2bf_rne(v.x);
  o.y = f2bf_rne(v.y);
  o.z = f2bf_rne(v.z);
  o.w = f2bf_rne(v.w);
  ((ushort4*)out)[idx] = o;
}

// ---------------- QKV projection GEMM (m97 structure) ----------------
// C[m,n] = sum_k A[m,k] * W[n,k] + bias[n]  (A: M x K bf16, W: N x K bf16)
// 128x128 block tile, BK=32, 256 threads = 4 waves in 2x2, each wave 64x64
// (4x4 MFMA 16x16x32). global_load_lds width-16 staging (unpadded LDS —
// lane-contiguous chunk layout required). Output fp32. grid.z -> {Wq,Wk,Wv}.
__global__ __launch_bounds__(256) void qkv_gemm(
    const unsigned short* __restrict__ A,
    const unsigned short* __restrict__ W0, const unsigned short* __restrict__ W1,
    const unsigned short* __restrict__ W2,
    const float* __restrict__ b0, const float* __restrict__ b1,
    const float* __restrict__ b2,
    float* __restrict__ O0, float* __restrict__ O1, float* __restrict__ O2) {
  const int K = HID;
  const int N = HID;
  const int z = blockIdx.z;
  const unsigned short* __restrict__ W = (z == 0) ? W0 : (z == 1) ? W1 : W2;
  const float* __restrict__ bias = (z == 0) ? b0 : (z == 1) ? b1 : b2;
  float* __restrict__ O = (z == 0) ? O0 : (z == 1) ? O1 : O2;

  __shared__ __align__(16) unsigned short As[BM * BK];  // 8 KB
  __shared__ __align__(16) unsigned short Bs[BN * BK];  // 8 KB

  const int tid = threadIdx.x;
  const int w = tid >> 6;
  const int lane = tid & 63;
  const int m0 = blockIdx.x * BM;
  const int n0 = blockIdx.y * BN;

  // staging: 16 chunks of 1 KB (16 rows x 64 B); wave w owns chunks 2w, 2w+1
  // of A and of B. Lane l's 16 B lands at chunk_base + l*16 (HW rule), which
  // equals row-major [row= c*16 + l/4][col=(l&3)*8] for the unpadded tile.
  const int c0 = w * 2, c1 = w * 2 + 1;
  const int scol = (lane & 3) * 8;
  const int r0 = c0 * 16 + (lane >> 2);
  const int r1 = c1 * 16 + (lane >> 2);

  const unsigned short* gA0 = A + (size_t)(m0 + r0) * K + scol;
  const unsigned short* gA1 = A + (size_t)(m0 + r1) * K + scol;
  const unsigned short* gB0 = W + (size_t)(n0 + r0) * K + scol;
  const unsigned short* gB1 = W + (size_t)(n0 + r1) * K + scol;
  unsigned short* lA0 = As + c0 * 512;
  unsigned short* lA1 = As + c1 * 512;
  unsigned short* lB0 = Bs + c0 * 512;
  unsigned short* lB1 = Bs + c1 * 512;

  const int lrow = lane & 15;
  const int qd = lane >> 4;              // 0..3
  const int arow = (w & 1) * 64 + lrow;  // wave m-offset
  const int brow = (w >> 1) * 64 + lrow; // wave n-offset

  floatx4 acc[4][4] = {};

  for (int k0 = 0; k0 < K; k0 += BK) {
    glds16(gA0 + k0, lA0);
    glds16(gA1 + k0, lA1);
    glds16(gB0 + k0, lB0);
    glds16(gB1 + k0, lB1);
    __syncthreads();

    short8 af[4], bf[4];
    #pragma unroll
    for (int im = 0; im < 4; ++im)
      af[im] = *(const short8*)(As + (arow + im * 16) * BK + qd * 8);
    #pragma unroll
    for (int in = 0; in < 4; ++in)
      bf[in] = *(const short8*)(Bs + (brow + in * 16) * BK + qd * 8);

    #pragma unroll
    for (int im = 0; im < 4; ++im)
      #pragma unroll
      for (int in = 0; in < 4; ++in)
        acc[im][in] = __builtin_amdgcn_mfma_f32_16x16x32_bf16(af[im], bf[in], acc[im][in], 0, 0, 0);
    __syncthreads();
  }

  // epilogue: C/D layout col = lane&15, row = quad*4 + r
  #pragma unroll
  for (int im = 0; im < 4; ++im) {
    #pragma unroll
    for (int in = 0; in < 4; ++in) {
      const int col = n0 + (w >> 1) * 64 + in * 16 + lrow;
      const float bb = bias[col];
      #pragma unroll
      for (int r = 0; r < 4; ++r) {
        const int row = m0 + (w & 1) * 64 + im * 16 + (qd << 2) + r;
        O[(size_t)row * N + col] = acc[im][in][r] + bb;
      }
    }
  }
}

// ---------------- log-sparse attention ----------------
// 16 lanes per query (lane covers 4 dims, float4), 4 queries per wave,
// 16 queries per 256-thread block. Keys: j = i, i-1, i-2, i-4, ...
// Q,K,V layout: [b, s, h, d] fp32 (GEMM output layout, n = h*64+d).
__global__ __launch_bounds__(256) void logsparse_attn(
    const float* __restrict__ Q, const float* __restrict__ K,
    const float* __restrict__ V, const float* __restrict__ mask,
    float* __restrict__ out) {
  const int tid = threadIdx.x;
  const int g = tid >> 4;          // query group in block 0..15
  const int l = tid & 15;          // lane in group
  const int qglob = blockIdx.x * 16 + g;

  const int i = qglob & (S_LEN - 1);
  const int h = (qglob >> 11) & (NHEADS - 1);
  const int b = qglob >> 15;

  const size_t base = (size_t)b * S_LEN * HID + h * HDIM + l * 4;

  const float4 q4 = *(const float4*)(Q + base + (size_t)i * HID);

  int js[12];
  js[0] = i;
  int nj = 1;
  for (int dlt = 1; dlt <= i; dlt <<= 1) js[nj++] = i - dlt;
  #pragma unroll
  for (int t = 1; t < 12; ++t)
    if (t >= nj) js[t] = i;  // harmless pad

  float s[12];
  #pragma unroll
  for (int t = 0; t < 12; ++t) {
    const int j = js[t];
    const float4 k4 = *(const float4*)(K + base + (size_t)j * HID);
    float p = q4.x * k4.x + q4.y * k4.y + q4.z * k4.z + q4.w * k4.w;
    p += __shfl_xor(p, 1, 64);
    p += __shfl_xor(p, 2, 64);
    p += __shfl_xor(p, 4, 64);
    p += __shfl_xor(p, 8, 64);
    s[t] = (t < nj) ? (p * 0.125f + mask[b * S_LEN + j]) : -1e30f;
  }

  float mx = s[0];
  #pragma unroll
  for (int t = 1; t < 12; ++t) mx = fmaxf(mx, s[t]);
  float lsum = 0.f;
  #pragma unroll
  for (int t = 0; t < 12; ++t) { s[t] = __expf(s[t] - mx); lsum += s[t]; }
  const float inv = 1.f / lsum;

  float4 o = {0.f, 0.f, 0.f, 0.f};
  #pragma unroll
  for (int t = 0; t < 12; ++t) {
    const float4 v4 = *(const float4*)(V + base + (size_t)js[t] * HID);
    o.x += s[t] * v4.x;
    o.y += s[t] * v4.y;
    o.z += s[t] * v4.z;
    o.w += s[t] * v4.w;
  }
  o.x *= inv; o.y *= inv; o.z *= inv; o.w *= inv;
  *(float4*)(out + base + (size_t)i * HID) = o;
}

// ---------------- launch ----------------
extern "C" void kernel_launch(void* const* d_in, const int* in_sizes, int n_in,
                              void* d_out, int out_size, void* d_ws, size_t ws_size,
                              hipStream_t stream) {
  const float* hs   = (const float*)d_in[0];
  const float* mask = (const float*)d_in[1];
  const float* Wq   = (const float*)d_in[2];
  const float* bq   = (const float*)d_in[3];
  const float* Wk   = (const float*)d_in[4];
  const float* bk   = (const float*)d_in[5];
  const float* Wv   = (const float*)d_in[6];
  const float* bv   = (const float*)d_in[7];
  float* out = (float*)d_out;

  // workspace layout
  unsigned short* hsb = (unsigned short*)d_ws;                  // M*H bf16
  unsigned short* wqb = hsb + (size_t)M_ROWS * HID;             // H*H bf16
  unsigned short* wkb = wqb + (size_t)HID * HID;
  unsigned short* wvb = wkb + (size_t)HID * HID;
  float* Qf = (float*)(wvb + (size_t)HID * HID);                // M*H fp32
  float* Kf = Qf + (size_t)M_ROWS * HID;
  float* Vf = Kf + (size_t)M_ROWS * HID;

  // casts
  {
    int n4 = (M_ROWS * HID) / 4;
    cast_f32_bf16<<<n4 / 256, 256, 0, stream>>>(hs, hsb, n4);
    int w4 = (HID * HID) / 4;
    cast_f32_bf16<<<w4 / 256, 256, 0, stream>>>(Wq, wqb, w4);
    cast_f32_bf16<<<w4 / 256, 256, 0, stream>>>(Wk, wkb, w4);
    cast_f32_bf16<<<w4 / 256, 256, 0, stream>>>(Wv, wvb, w4);
  }

  // QKV projections
  {
    dim3 grid(M_ROWS / BM, HID / BN, 3);
    qkv_gemm<<<grid, 256, 0, stream>>>(hsb, wqb, wkb, wvb, bq, bk, bv, Qf, Kf, Vf);
  }

  // sparse attention: 16 queries per block
  {
    int blocks = (BATCH * NHEADS * S_LEN) / 16;   // 8192
    logsparse_attn<<<blocks, 256, 0, stream>>>(Qf, Kf, Vf, mask, out);
  }
}

// Round 3
// 195.218 us; speedup vs baseline: 1.8492x; 1.1931x over previous
//
#include <hip/hip_runtime.h>
#include <hip/hip_bf16.h>

// Problem dims (fixed by setup_inputs):
//   B=4, S=2048, H=1024, NH=16, D=64, M = B*S = 8192
#define S_LEN   2048
#define NHEADS  16
#define HDIM    64
#define HID     1024
#define BATCH   4
#define M_ROWS  (BATCH * S_LEN)   // 8192

#define BM 128
#define BN 128
#define BK 32

typedef __attribute__((ext_vector_type(8))) short short8;
typedef __attribute__((ext_vector_type(4))) float floatx4;

__device__ __forceinline__ unsigned short f2bf_rne(float x) {
  union { float f; unsigned u; } v; v.f = x;
  unsigned r = v.u + 0x7fffu + ((v.u >> 16) & 1u);
  return (unsigned short)(r >> 16);
}

__device__ __forceinline__ float bf2f(unsigned short u) {
  union { unsigned u; float f; } c; c.u = ((unsigned)u) << 16;
  return c.f;
}

__device__ __forceinline__ void glds16(const unsigned short* g, unsigned short* l) {
  __builtin_amdgcn_global_load_lds(
      (const __attribute__((address_space(1))) unsigned int*)g,
      (__attribute__((address_space(3))) unsigned int*)l, 16, 0, 0);
}

// ---------------- fp32 -> bf16 cast, all 4 tensors in one dispatch ----------
// quad ranges: [0, HS4) -> hs; then 3 x W4 for Wq, Wk, Wv.
#define HS4 (M_ROWS * HID / 4)        // 2097152
#define W4  (HID * HID / 4)           // 262144
__global__ __launch_bounds__(256) void cast_all(
    const float* __restrict__ hs, const float* __restrict__ Wq,
    const float* __restrict__ Wk, const float* __restrict__ Wv,
    unsigned short* __restrict__ hsb, unsigned short* __restrict__ wqb,
    unsigned short* __restrict__ wkb, unsigned short* __restrict__ wvb) {
  int idx = blockIdx.x * 256 + threadIdx.x;
  const float* in;
  unsigned short* out;
  int off;
  if (idx < HS4) {
    in = hs; out = hsb; off = idx;
  } else {
    int r = idx - HS4;
    int seg = r >> 18;          // W4 = 2^18
    off = r & (W4 - 1);
    in  = (seg == 0) ? Wq  : (seg == 1) ? Wk  : Wv;
    out = (seg == 0) ? wqb : (seg == 1) ? wkb : wvb;
  }
  float4 v = ((const float4*)in)[off];
  ushort4 o;
  o.x = f2bf_rne(v.x);
  o.y = f2bf_rne(v.y);
  o.z = f2bf_rne(v.z);
  o.w = f2bf_rne(v.w);
  ((ushort4*)out)[off] = o;
}

// ---------------- QKV projection GEMM (m97 structure) ----------------
// C[m,n] = bf16(sum_k A[m,k] * W[n,k] + bias[n])  (A: M x K bf16, W: N x K bf16)
// 128x128 block tile, BK=32, 256 threads = 4 waves in 2x2, each wave 64x64
// (4x4 MFMA 16x16x32). global_load_lds width-16 staging. Output bf16.
__global__ __launch_bounds__(256) void qkv_gemm(
    const unsigned short* __restrict__ A,
    const unsigned short* __restrict__ W0, const unsigned short* __restrict__ W1,
    const unsigned short* __restrict__ W2,
    const float* __restrict__ b0, const float* __restrict__ b1,
    const float* __restrict__ b2,
    unsigned short* __restrict__ O0, unsigned short* __restrict__ O1,
    unsigned short* __restrict__ O2) {
  const int K = HID;
  const int N = HID;
  const int z = blockIdx.z;
  const unsigned short* __restrict__ W = (z == 0) ? W0 : (z == 1) ? W1 : W2;
  const float* __restrict__ bias = (z == 0) ? b0 : (z == 1) ? b1 : b2;
  unsigned short* __restrict__ O = (z == 0) ? O0 : (z == 1) ? O1 : O2;

  __shared__ __align__(16) unsigned short As[BM * BK];  // 8 KB
  __shared__ __align__(16) unsigned short Bs[BN * BK];  // 8 KB

  const int tid = threadIdx.x;
  const int w = tid >> 6;
  const int lane = tid & 63;
  const int m0 = blockIdx.x * BM;
  const int n0 = blockIdx.y * BN;

  // staging: 16 chunks of 1 KB (16 rows x 64 B); wave w owns chunks 2w, 2w+1
  // of A and of B. Lane l's 16 B lands at chunk_base + l*16 (HW rule) ==
  // row-major [row = c*16 + l/4][col = (l&3)*8] of the unpadded tile.
  const int c0 = w * 2, c1 = w * 2 + 1;
  const int scol = (lane & 3) * 8;
  const int r0 = c0 * 16 + (lane >> 2);
  const int r1 = c1 * 16 + (lane >> 2);

  const unsigned short* gA0 = A + (size_t)(m0 + r0) * K + scol;
  const unsigned short* gA1 = A + (size_t)(m0 + r1) * K + scol;
  const unsigned short* gB0 = W + (size_t)(n0 + r0) * K + scol;
  const unsigned short* gB1 = W + (size_t)(n0 + r1) * K + scol;
  unsigned short* lA0 = As + c0 * 512;
  unsigned short* lA1 = As + c1 * 512;
  unsigned short* lB0 = Bs + c0 * 512;
  unsigned short* lB1 = Bs + c1 * 512;

  const int lrow = lane & 15;
  const int qd = lane >> 4;              // 0..3
  const int arow = (w & 1) * 64 + lrow;  // wave m-offset
  const int brow = (w >> 1) * 64 + lrow; // wave n-offset

  floatx4 acc[4][4] = {};

  for (int k0 = 0; k0 < K; k0 += BK) {
    glds16(gA0 + k0, lA0);
    glds16(gA1 + k0, lA1);
    glds16(gB0 + k0, lB0);
    glds16(gB1 + k0, lB1);
    __syncthreads();

    short8 af[4], bf[4];
    #pragma unroll
    for (int im = 0; im < 4; ++im)
      af[im] = *(const short8*)(As + (arow + im * 16) * BK + qd * 8);
    #pragma unroll
    for (int in = 0; in < 4; ++in)
      bf[in] = *(const short8*)(Bs + (brow + in * 16) * BK + qd * 8);

    #pragma unroll
    for (int im = 0; im < 4; ++im)
      #pragma unroll
      for (int in = 0; in < 4; ++in)
        acc[im][in] = __builtin_amdgcn_mfma_f32_16x16x32_bf16(af[im], bf[in], acc[im][in], 0, 0, 0);
    __syncthreads();
  }

  // epilogue: C/D layout col = lane&15, row = quad*4 + r; write bf16
  #pragma unroll
  for (int im = 0; im < 4; ++im) {
    #pragma unroll
    for (int in = 0; in < 4; ++in) {
      const int col = n0 + (w >> 1) * 64 + in * 16 + lrow;
      const float bb = bias[col];
      #pragma unroll
      for (int r = 0; r < 4; ++r) {
        const int row = m0 + (w & 1) * 64 + im * 16 + (qd << 2) + r;
        O[(size_t)row * N + col] = f2bf_rne(acc[im][in][r] + bb);
      }
    }
  }
}

// ---------------- log-sparse attention ----------------
// 8 lanes per query (lane covers 8 dims, 16 B bf16 load), 8 queries per wave,
// 32 queries per 256-thread block. Keys: j = i, i-1, i-2, i-4, ...
// Q,K,V layout: bf16 [b, s, h*64+d]. Output fp32.
__global__ __launch_bounds__(256) void logsparse_attn(
    const unsigned short* __restrict__ Q, const unsigned short* __restrict__ K,
    const unsigned short* __restrict__ V, const float* __restrict__ mask,
    float* __restrict__ out) {
  const int tid = threadIdx.x;
  const int l = tid & 7;                       // lane in query group
  const int qglob = blockIdx.x * 32 + (tid >> 3);

  const int i = qglob & (S_LEN - 1);
  const int h = (qglob >> 11) & (NHEADS - 1);
  const int b = qglob >> 15;

  const size_t base = (size_t)b * S_LEN * HID + h * HDIM + l * 8;

  // Q fragment -> fp32
  float qf[8];
  {
    short8 q8 = *(const short8*)(Q + base + (size_t)i * HID);
    #pragma unroll
    for (int e = 0; e < 8; ++e) qf[e] = bf2f((unsigned short)q8[e]);
  }

  int js[12];
  js[0] = i;
  int nj = 1;
  for (int dlt = 1; dlt <= i; dlt <<= 1) js[nj++] = i - dlt;

  float s[12];
  #pragma unroll
  for (int t = 0; t < 12; ++t) {
    if (t < nj) {
      const int j = js[t];
      short8 k8 = *(const short8*)(K + base + (size_t)j * HID);
      float p = 0.f;
      #pragma unroll
      for (int e = 0; e < 8; ++e) p += qf[e] * bf2f((unsigned short)k8[e]);
      p += __shfl_xor(p, 1, 64);
      p += __shfl_xor(p, 2, 64);
      p += __shfl_xor(p, 4, 64);
      s[t] = p * 0.125f + mask[b * S_LEN + j];
    } else {
      s[t] = -1e30f;
    }
  }

  float mx = s[0];
  #pragma unroll
  for (int t = 1; t < 12; ++t) mx = fmaxf(mx, s[t]);
  float lsum = 0.f;
  #pragma unroll
  for (int t = 0; t < 12; ++t) { s[t] = __expf(s[t] - mx); lsum += s[t]; }
  const float inv = 1.f / lsum;

  float o[8] = {};
  #pragma unroll
  for (int t = 0; t < 12; ++t) {
    if (t < nj) {
      short8 v8 = *(const short8*)(V + base + (size_t)js[t] * HID);
      #pragma unroll
      for (int e = 0; e < 8; ++e) o[e] += s[t] * bf2f((unsigned short)v8[e]);
    }
  }

  float* op = out + base + (size_t)i * HID;
  float4 o0 = {o[0] * inv, o[1] * inv, o[2] * inv, o[3] * inv};
  float4 o1 = {o[4] * inv, o[5] * inv, o[6] * inv, o[7] * inv};
  *(float4*)(op) = o0;
  *(float4*)(op + 4) = o1;
}

// ---------------- launch ----------------
extern "C" void kernel_launch(void* const* d_in, const int* in_sizes, int n_in,
                              void* d_out, int out_size, void* d_ws, size_t ws_size,
                              hipStream_t stream) {
  const float* hs   = (const float*)d_in[0];
  const float* mask = (const float*)d_in[1];
  const float* Wq   = (const float*)d_in[2];
  const float* bq   = (const float*)d_in[3];
  const float* Wk   = (const float*)d_in[4];
  const float* bk   = (const float*)d_in[5];
  const float* Wv   = (const float*)d_in[6];
  const float* bv   = (const float*)d_in[7];
  float* out = (float*)d_out;

  // workspace layout (all bf16)
  unsigned short* hsb = (unsigned short*)d_ws;                  // M*H
  unsigned short* wqb = hsb + (size_t)M_ROWS * HID;             // H*H
  unsigned short* wkb = wqb + (size_t)HID * HID;
  unsigned short* wvb = wkb + (size_t)HID * HID;
  unsigned short* Qb = wvb + (size_t)HID * HID;                 // M*H
  unsigned short* Kb = Qb + (size_t)M_ROWS * HID;
  unsigned short* Vb = Kb + (size_t)M_ROWS * HID;

  // casts: one dispatch for hs + Wq + Wk + Wv
  {
    int quads = HS4 + 3 * W4;                 // 2883584
    cast_all<<<quads / 256, 256, 0, stream>>>(hs, Wq, Wk, Wv, hsb, wqb, wkb, wvb);
  }

  // QKV projections
  {
    dim3 grid(M_ROWS / BM, HID / BN, 3);
    qkv_gemm<<<grid, 256, 0, stream>>>(hsb, wqb, wkb, wvb, bq, bk, bv, Qb, Kb, Vb);
  }

  // sparse attention: 32 queries per 256-thread block
  {
    int blocks = (BATCH * NHEADS * S_LEN) / 32;   // 4096
    logsparse_attn<<<blocks, 256, 0, stream>>>(Qb, Kb, Vb, mask, out);
  }
}

// Round 4
// 185.989 us; speedup vs baseline: 1.9410x; 1.0496x over previous
//
#include <hip/hip_runtime.h>
#include <hip/hip_bf16.h>

// Problem dims (fixed by setup_inputs):
//   B=4, S=2048, H=1024, NH=16, D=64, M = B*S = 8192
#define S_LEN   2048
#define NHEADS  16
#define HDIM    64
#define HID     1024
#define BATCH   4
#define M_ROWS  (BATCH * S_LEN)   // 8192

#define BM 128
#define BN 128
#define BK 64

typedef __attribute__((ext_vector_type(8))) short short8;
typedef __attribute__((ext_vector_type(4))) float floatx4;

__device__ __forceinline__ unsigned short f2bf_rne(float x) {
  union { float f; unsigned u; } v; v.f = x;
  unsigned r = v.u + 0x7fffu + ((v.u >> 16) & 1u);
  return (unsigned short)(r >> 16);
}

__device__ __forceinline__ float bf2f(unsigned short u) {
  union { unsigned u; float f; } c; c.u = ((unsigned)u) << 16;
  return c.f;
}

__device__ __forceinline__ void glds16(const unsigned short* g, unsigned short* l) {
  __builtin_amdgcn_global_load_lds(
      (const __attribute__((address_space(1))) unsigned int*)g,
      (__attribute__((address_space(3))) unsigned int*)l, 16, 0, 0);
}

// ---------------- fp32 -> bf16 cast, all 4 tensors in one dispatch ----------
#define HS4 (M_ROWS * HID / 4)        // 2097152
#define W4  (HID * HID / 4)           // 262144
__global__ __launch_bounds__(256) void cast_all(
    const float* __restrict__ hs, const float* __restrict__ Wq,
    const float* __restrict__ Wk, const float* __restrict__ Wv,
    unsigned short* __restrict__ hsb, unsigned short* __restrict__ wqb,
    unsigned short* __restrict__ wkb, unsigned short* __restrict__ wvb) {
  int idx = blockIdx.x * 256 + threadIdx.x;
  const float* in;
  unsigned short* out;
  int off;
  if (idx < HS4) {
    in = hs; out = hsb; off = idx;
  } else {
    int r = idx - HS4;
    int seg = r >> 18;          // W4 = 2^18
    off = r & (W4 - 1);
    in  = (seg == 0) ? Wq  : (seg == 1) ? Wk  : Wv;
    out = (seg == 0) ? wqb : (seg == 1) ? wkb : wvb;
  }
  float4 v = ((const float4*)in)[off];
  ushort4 o;
  o.x = f2bf_rne(v.x);
  o.y = f2bf_rne(v.y);
  o.z = f2bf_rne(v.z);
  o.w = f2bf_rne(v.w);
  ((ushort4*)out)[off] = o;
}

// ---------------- QKV projection GEMM ----------------
// C[m,n] = bf16(sum_k A[m,k]*W[n,k] + bias[n]); A: MxK bf16, W: NxK bf16.
// 128x128 tile, BK=64, 4 waves (2x2), each wave 64x64 via 4x4 MFMA 16x16x32
// (2 K-substeps per BK). global_load_lds width-16 staging with XOR bank
// swizzle implemented on the SOURCE side: LDS chunk (R, c^R&7) holds global
// chunk (R, c). Row = 128 B = all 32 banks, so any 8-lane phase of a
// ds_read_b128 covers all 8 bank groups -> conflict-free.
__global__ __launch_bounds__(256) void qkv_gemm(
    const unsigned short* __restrict__ A,
    const unsigned short* __restrict__ W0, const unsigned short* __restrict__ W1,
    const unsigned short* __restrict__ W2,
    const float* __restrict__ b0, const float* __restrict__ b1,
    const float* __restrict__ b2,
    unsigned short* __restrict__ O0, unsigned short* __restrict__ O1,
    unsigned short* __restrict__ O2) {
  const int K = HID;
  const int N = HID;
  const int z = blockIdx.z;
  const unsigned short* __restrict__ W = (z == 0) ? W0 : (z == 1) ? W1 : W2;
  const float* __restrict__ bias = (z == 0) ? b0 : (z == 1) ? b1 : b2;
  unsigned short* __restrict__ O = (z == 0) ? O0 : (z == 1) ? O1 : O2;

  __shared__ __align__(16) unsigned short As[BM * BK];  // 16 KB
  __shared__ __align__(16) unsigned short Bs[BN * BK];  // 16 KB

  const int tid = threadIdx.x;
  const int w = tid >> 6;
  const int lane = tid & 63;
  const int m0 = blockIdx.x * BM;
  const int n0 = blockIdx.y * BN;

  // staging: 16 segments of 1 KB, each = 8 rows x 8 chunks(16B). Wave w owns
  // segments w*4+u (u=0..3). Lane l -> slot l: local row lr=l>>3, LDS chunk
  // l&7; it must hold global chunk cc = (l&7) ^ lr  (since R&7 == lr).
  const int lr = lane >> 3;
  const int cc = (lane & 7) ^ lr;
  const unsigned short* gA[4];
  const unsigned short* gB[4];
  unsigned short* lA[4];
  unsigned short* lB[4];
  #pragma unroll
  for (int u = 0; u < 4; ++u) {
    const int seg = w * 4 + u;
    const int r = seg * 8 + lr;
    gA[u] = A + (size_t)(m0 + r) * K + cc * 8;
    gB[u] = W + (size_t)(n0 + r) * K + cc * 8;
    lA[u] = As + seg * 512;
    lB[u] = Bs + seg * 512;
  }

  const int lrow = lane & 15;
  const int qd = lane >> 4;              // 0..3
  const int sw = lrow & 7;               // read-side swizzle key (R&7)
  const int arow = (w & 1) * 64 + lrow;  // wave m-offset
  const int brow = (w >> 1) * 64 + lrow; // wave n-offset

  floatx4 acc[4][4] = {};

  for (int k0 = 0; k0 < K; k0 += BK) {
    #pragma unroll
    for (int u = 0; u < 4; ++u) {
      glds16(gA[u] + k0, lA[u]);
      glds16(gB[u] + k0, lB[u]);
    }
    __syncthreads();

    #pragma unroll
    for (int kk = 0; kk < 2; ++kk) {
      const int cp = (((kk << 2) | qd) ^ sw) * 8;  // swizzled chunk -> shorts
      short8 af[4], bf[4];
      #pragma unroll
      for (int im = 0; im < 4; ++im)
        af[im] = *(const short8*)(As + (arow + im * 16) * BK + cp);
      #pragma unroll
      for (int in = 0; in < 4; ++in)
        bf[in] = *(const short8*)(Bs + (brow + in * 16) * BK + cp);

      #pragma unroll
      for (int im = 0; im < 4; ++im)
        #pragma unroll
        for (int in = 0; in < 4; ++in)
          acc[im][in] = __builtin_amdgcn_mfma_f32_16x16x32_bf16(af[im], bf[in], acc[im][in], 0, 0, 0);
    }
    __syncthreads();
  }

  // epilogue: C/D layout col = lane&15, row = quad*4 + r; write bf16
  #pragma unroll
  for (int im = 0; im < 4; ++im) {
    #pragma unroll
    for (int in = 0; in < 4; ++in) {
      const int col = n0 + (w >> 1) * 64 + in * 16 + lrow;
      const float bb = bias[col];
      #pragma unroll
      for (int r = 0; r < 4; ++r) {
        const int row = m0 + (w & 1) * 64 + im * 16 + (qd << 2) + r;
        O[(size_t)row * N + col] = f2bf_rne(acc[im][in][r] + bb);
      }
    }
  }
}

// ---------------- log-sparse attention ----------------
// 8 lanes per query (lane = 8 dims, 16 B bf16 loads), 32 queries per block.
// ALL K/V/Q/mask loads are issued unconditionally up front (padded key slots
// clamped to j=i, a valid cached row) so the gathers overlap instead of
// serializing on per-load vmcnt(0).
__global__ __launch_bounds__(256) void logsparse_attn(
    const unsigned short* __restrict__ Q, const unsigned short* __restrict__ K,
    const unsigned short* __restrict__ V, const float* __restrict__ mask,
    float* __restrict__ out) {
  const int tid = threadIdx.x;
  const int l = tid & 7;
  const int qglob = blockIdx.x * 32 + (tid >> 3);

  const int i = qglob & (S_LEN - 1);
  const int h = (qglob >> 11) & (NHEADS - 1);
  const int b = qglob >> 15;

  const size_t base = (size_t)b * S_LEN * HID + h * HDIM + l * 8;

  int js[12];
  js[0] = i;
  int nj = 1;
  for (int d = 1; d <= i; d <<= 1) js[nj++] = i - d;
  #pragma unroll
  for (int t = 0; t < 12; ++t)
    if (t >= nj) js[t] = i;   // clamp: valid row, contributes 0 after mask

  // batch prefetch: 12 K + 12 V + 1 Q + 12 mask loads, no guards
  short8 k8[12], v8[12];
  #pragma unroll
  for (int t = 0; t < 12; ++t)
    k8[t] = *(const short8*)(K + base + (size_t)js[t] * HID);
  const short8 q8 = *(const short8*)(Q + base + (size_t)i * HID);
  #pragma unroll
  for (int t = 0; t < 12; ++t)
    v8[t] = *(const short8*)(V + base + (size_t)js[t] * HID);
  float mk[12];
  #pragma unroll
  for (int t = 0; t < 12; ++t)
    mk[t] = mask[b * S_LEN + js[t]];

  float qf[8];
  #pragma unroll
  for (int e = 0; e < 8; ++e) qf[e] = bf2f((unsigned short)q8[e]);

  float s[12];
  #pragma unroll
  for (int t = 0; t < 12; ++t) {
    float p = 0.f;
    #pragma unroll
    for (int e = 0; e < 8; ++e) p += qf[e] * bf2f((unsigned short)k8[t][e]);
    p += __shfl_xor(p, 1, 64);
    p += __shfl_xor(p, 2, 64);
    p += __shfl_xor(p, 4, 64);
    s[t] = (t < nj) ? (p * 0.125f + mk[t]) : -1e30f;
  }

  float mx = s[0];
  #pragma unroll
  for (int t = 1; t < 12; ++t) mx = fmaxf(mx, s[t]);
  float lsum = 0.f;
  #pragma unroll
  for (int t = 0; t < 12; ++t) { s[t] = __expf(s[t] - mx); lsum += s[t]; }
  const float inv = 1.f / lsum;

  float o[8] = {};
  #pragma unroll
  for (int t = 0; t < 12; ++t) {
    #pragma unroll
    for (int e = 0; e < 8; ++e) o[e] += s[t] * bf2f((unsigned short)v8[t][e]);
  }

  float* op = out + base + (size_t)i * HID;
  float4 o0 = {o[0] * inv, o[1] * inv, o[2] * inv, o[3] * inv};
  float4 o1 = {o[4] * inv, o[5] * inv, o[6] * inv, o[7] * inv};
  *(float4*)(op) = o0;
  *(float4*)(op + 4) = o1;
}

// ---------------- launch ----------------
extern "C" void kernel_launch(void* const* d_in, const int* in_sizes, int n_in,
                              void* d_out, int out_size, void* d_ws, size_t ws_size,
                              hipStream_t stream) {
  const float* hs   = (const float*)d_in[0];
  const float* mask = (const float*)d_in[1];
  const float* Wq   = (const float*)d_in[2];
  const float* bq   = (const float*)d_in[3];
  const float* Wk   = (const float*)d_in[4];
  const float* bk   = (const float*)d_in[5];
  const float* Wv   = (const float*)d_in[6];
  const float* bv   = (const float*)d_in[7];
  float* out = (float*)d_out;

  // workspace layout (all bf16)
  unsigned short* hsb = (unsigned short*)d_ws;                  // M*H
  unsigned short* wqb = hsb + (size_t)M_ROWS * HID;             // H*H
  unsigned short* wkb = wqb + (size_t)HID * HID;
  unsigned short* wvb = wkb + (size_t)HID * HID;
  unsigned short* Qb = wvb + (size_t)HID * HID;                 // M*H
  unsigned short* Kb = Qb + (size_t)M_ROWS * HID;
  unsigned short* Vb = Kb + (size_t)M_ROWS * HID;

  // casts: one dispatch for hs + Wq + Wk + Wv
  {
    int quads = HS4 + 3 * W4;                 // 2883584
    cast_all<<<quads / 256, 256, 0, stream>>>(hs, Wq, Wk, Wv, hsb, wqb, wkb, wvb);
  }

  // QKV projections
  {
    dim3 grid(M_ROWS / BM, HID / BN, 3);
    qkv_gemm<<<grid, 256, 0, stream>>>(hsb, wqb, wkb, wvb, bq, bk, bv, Qb, Kb, Vb);
  }

  // sparse attention: 32 queries per 256-thread block
  {
    int blocks = (BATCH * NHEADS * S_LEN) / 32;   // 4096
    logsparse_attn<<<blocks, 256, 0, stream>>>(Qb, Kb, Vb, mask, out);
  }
}